// Round 6
// baseline (428.614 us; speedup 1.0000x reference)
//
#include <hip/hip_runtime.h>
#include <hip/hip_bf16.h>

#define TDIM 2048
#define DDIM 768
#define IDIM 2048
#define NEXP 8

typedef __bf16 v8bf __attribute__((ext_vector_type(8)));
typedef float v4f __attribute__((ext_vector_type(4)));
typedef int   v4i __attribute__((ext_vector_type(4)));
typedef float v4ff __attribute__((ext_vector_type(4)));

#define MFMA_B16(A,B,C) __builtin_amdgcn_mfma_f32_16x16x32_bf16(A,B,C,0,0,0)

typedef __attribute__((address_space(1))) const unsigned int* gas_t;
typedef __attribute__((address_space(3))) unsigned int* las_t;

__device__ __forceinline__ void gload16(const void* g, void* l) {
  __builtin_amdgcn_global_load_lds((gas_t)g, (las_t)l, 16, 0, 0);
}

// ---------------- merged router + x-pack + weight-pack ----------------
// blocks [0,512):      router, 4 tokens/block (1 per wave)
// blocks [512,1280):   x fp32 -> bf16 (linear)
// blocks [1280,6464):  weight tiles -> bf16, [128 rows][64 cols] XOR-swizzled
//   tile layout: linear byte L holds element (row=L/128, colbyte=(L%128)^((row&7)<<4)).
//   Per thread: 64 dst bytes = 4x16B chunks; 8 loads issued back-to-back for ILP.
__global__ __launch_bounds__(256)
void pack_all_kernel(const int* __restrict__ qg, const int* __restrict__ qu,
                     const int* __restrict__ qd,
                     const float* __restrict__ sg, const float* __restrict__ su,
                     const float* __restrict__ sd, const float* __restrict__ x,
                     const float* __restrict__ rw,
                     __hip_bfloat16* __restrict__ wgT, __hip_bfloat16* __restrict__ wuT,
                     __hip_bfloat16* __restrict__ wdT, __hip_bfloat16* __restrict__ sgT,
                     __hip_bfloat16* __restrict__ suT, __hip_bfloat16* __restrict__ sdT,
                     __hip_bfloat16* __restrict__ xb,
                     int* __restrict__ cnt, int* __restrict__ lists, float* __restrict__ wt)
{
  const int b = blockIdx.x;
  const int tid = threadIdx.x;

  if (b < 512) {  // ---------------- router ----------------
    const int t = b * 4 + (tid >> 6);
    const int lane = tid & 63;
    const float* xp = x + (size_t)t * DDIM;
    float4 xv0 = *(const float4*)(xp + lane * 4);
    float4 xv1 = *(const float4*)(xp + 256 + lane * 4);
    float4 xv2 = *(const float4*)(xp + 512 + lane * 4);
    float logit[NEXP];
#pragma unroll
    for (int e = 0; e < NEXP; ++e) {
      const float* w = rw + (size_t)e * DDIM;
      float4 w0 = *(const float4*)(w + lane * 4);
      float4 w1 = *(const float4*)(w + 256 + lane * 4);
      float4 w2 = *(const float4*)(w + 512 + lane * 4);
      float p = xv0.x * w0.x + xv0.y * w0.y + xv0.z * w0.z + xv0.w * w0.w
              + xv1.x * w1.x + xv1.y * w1.y + xv1.z * w1.z + xv1.w * w1.w
              + xv2.x * w2.x + xv2.y * w2.y + xv2.z * w2.z + xv2.w * w2.w;
#pragma unroll
      for (int off = 32; off > 0; off >>= 1) p += __shfl_down(p, off, 64);
      logit[e] = p;
    }
    if (lane == 0) {
      float m = logit[0];
#pragma unroll
      for (int e = 1; e < NEXP; ++e) m = fmaxf(m, logit[e]);
      float pr[NEXP];
#pragma unroll
      for (int e = 0; e < NEXP; ++e) pr[e] = expf(logit[e] - m);
      int i0 = 0; float v0 = pr[0];
#pragma unroll
      for (int e = 1; e < NEXP; ++e) if (pr[e] > v0) { v0 = pr[e]; i0 = e; }
      int i1 = -1; float v1 = -1.f;
#pragma unroll
      for (int e = 0; e < NEXP; ++e) if (e != i0 && pr[e] > v1) { v1 = pr[e]; i1 = e; }
      float inv = 1.f / (v0 + v1);
      int p0 = atomicAdd(&cnt[i0], 1);
      lists[i0 * TDIM + p0] = t * 2;       // slot = t*2 + k
      wt[t * 2] = v0 * inv;
      int p1 = atomicAdd(&cnt[i1], 1);
      lists[i1 * TDIM + p1] = t * 2 + 1;
      wt[t * 2 + 1] = v1 * inv;
    }
    return;
  }

  if (b < 1280) {  // ---------------- x fp32 -> bf16 ----------------
    const size_t i = (size_t)(b - 512) * 2048 + tid * 8;
    float4 a0 = *(const float4*)(x + i);
    float4 a1 = *(const float4*)(x + i + 4);
    v8bf v;
    v[0] = (__bf16)a0.x; v[1] = (__bf16)a0.y; v[2] = (__bf16)a0.z; v[3] = (__bf16)a0.w;
    v[4] = (__bf16)a1.x; v[5] = (__bf16)a1.y; v[6] = (__bf16)a1.z; v[7] = (__bf16)a1.w;
    *(v8bf*)(xb + i) = v;
    return;
  }

  // ---------------- weight tiles ----------------
  const int wb = b - 1280;
  const void* src; __hip_bfloat16* dst; int NT, KT, isint, tile;
  if (wb < 1536)      { src = qg; dst = wgT; NT = 16; KT = 12; isint = 1; tile = wb; }
  else if (wb < 3072) { src = qu; dst = wuT; NT = 16; KT = 12; isint = 1; tile = wb - 1536; }
  else if (wb < 4608) { src = qd; dst = wdT; NT = 6;  KT = 32; isint = 1; tile = wb - 3072; }
  else if (wb < 4800) { src = sg; dst = sgT; NT = 16; KT = 12; isint = 0; tile = wb - 4608; }
  else if (wb < 4992) { src = su; dst = suT; NT = 16; KT = 12; isint = 0; tile = wb - 4800; }
  else                { src = sd; dst = sdT; NT = 6;  KT = 32; isint = 0; tile = wb - 4992; }
  const int kt = tile % KT;
  const int nt = (tile / KT) % NT;
  const int e  = tile / (KT * NT);
  const int Kk = KT * 64;

  const int row  = tid >> 1;           // 0..127
  const int half = tid & 1;            // which 64-byte half of the dst row
  const int xorm = (row & 7) << 4;
  const size_t srow = ((size_t)e * (NT * 128) + nt * 128 + row) * Kk + kt * 64;
  __hip_bfloat16* dptr = dst + (size_t)tile * 8192 + row * 64 + half * 32;

  if (isint) {
    const int* s = (const int*)src + srow;
    v4i r[8];
#pragma unroll
    for (int j = 0; j < 4; ++j) {
      const int k = ((half * 64 + j * 16) ^ xorm) >> 1;
      r[2 * j]     = __builtin_nontemporal_load((const v4i*)(s + k));
      r[2 * j + 1] = __builtin_nontemporal_load((const v4i*)(s + k) + 1);
    }
#pragma unroll
    for (int j = 0; j < 4; ++j) {
      v8bf v;
      v[0] = (__bf16)(float)r[2 * j][0];     v[1] = (__bf16)(float)r[2 * j][1];
      v[2] = (__bf16)(float)r[2 * j][2];     v[3] = (__bf16)(float)r[2 * j][3];
      v[4] = (__bf16)(float)r[2 * j + 1][0]; v[5] = (__bf16)(float)r[2 * j + 1][1];
      v[6] = (__bf16)(float)r[2 * j + 1][2]; v[7] = (__bf16)(float)r[2 * j + 1][3];
      *(v8bf*)(dptr + j * 8) = v;
    }
  } else {
    const float* s = (const float*)src + srow;
    v4ff r[8];
#pragma unroll
    for (int j = 0; j < 4; ++j) {
      const int k = ((half * 64 + j * 16) ^ xorm) >> 1;
      r[2 * j]     = *(const v4ff*)(s + k);
      r[2 * j + 1] = *((const v4ff*)(s + k) + 1);
    }
#pragma unroll
    for (int j = 0; j < 4; ++j) {
      v8bf v;
      v[0] = (__bf16)r[2 * j][0];     v[1] = (__bf16)r[2 * j][1];
      v[2] = (__bf16)r[2 * j][2];     v[3] = (__bf16)r[2 * j][3];
      v[4] = (__bf16)r[2 * j + 1][0]; v[5] = (__bf16)r[2 * j + 1][1];
      v[6] = (__bf16)r[2 * j + 1][2]; v[7] = (__bf16)r[2 * j + 1][3];
      *(v8bf*)(dptr + j * 8) = v;
    }
  }
}

// ---------------- unified gate+up GEMM, 128x64 tile, BK=64 ----------------
// blocks [0,4096): experts (e=b>>9, tm=(b>>5)&15, tn=b&31), gathered rows, out=he[slot]
// blocks [4096,4608): shared expert, dense rows, out=hs[token]
// 4 waves (2x2): per-wave output 64x32 -> acc 2x[4][2] = 64 regs; LDS 32KB; 3 waves/EU.
__global__ __launch_bounds__(256, 3)
void gateup_kernel(const __hip_bfloat16* __restrict__ xb,
                   const __hip_bfloat16* __restrict__ wgT, const __hip_bfloat16* __restrict__ wuT,
                   const __hip_bfloat16* __restrict__ sgT, const __hip_bfloat16* __restrict__ suT,
                   const float* __restrict__ es,
                   const int* __restrict__ cnt, const int* __restrict__ lists,
                   __hip_bfloat16* __restrict__ he, __hip_bfloat16* __restrict__ hs)
{
  const int b = blockIdx.x;
  int tm, tn, count;
  const char *wg, *wu;
  const int* listE = nullptr;
  __hip_bfloat16* hout;
  float sg, su;
  if (b < 4096) {
    const int e = b >> 9; tm = (b >> 5) & 15; tn = b & 31;
    count = cnt[e];
    if (tm * 128 >= count) return;
    const size_t base = (size_t)(e * 16 + (tn >> 1)) * (12 * 16384) + (tn & 1) * 8192;
    wg = (const char*)wgT + base;
    wu = (const char*)wuT + base;
    listE = lists + e * TDIM;
    sg = es[e * 3 + 0]; su = es[e * 3 + 1];
    hout = he;
  } else {
    const int b2 = b - 4096; tm = b2 >> 5; tn = b2 & 31;
    count = TDIM;
    const size_t base = (size_t)(tn >> 1) * (12 * 16384) + (tn & 1) * 8192;
    wg = (const char*)sgT + base;
    wu = (const char*)suT + base;
    sg = 1.f; su = 1.f;
    hout = hs;
  }

  __shared__ __align__(16) char As[16384];
  __shared__ __align__(16) char Bg[8192];
  __shared__ __align__(16) char Bu[8192];

  const int tid = threadIdx.x;
  const int lane = tid & 63;
  const int wid = tid >> 6;
  const int wr = wid >> 1, wc = wid & 1;
  const int lr16 = lane & 15, hk = lane >> 4;

  // A staging: per-lane pre-swizzled gather source addresses (linear LDS dest)
  const int cA = (((lane & 7) ^ (lane >> 3)) << 4);
  const char* aptr[4];
#pragma unroll
  for (int p = 0; p < 4; ++p) {
    const int row = p * 32 + wid * 8 + (lane >> 3);
    const int rg = tm * 128 + row;
    int tok;
    if (listE) { const int idx = rg < count ? rg : count - 1; tok = listE[idx] >> 1; }
    else tok = rg;
    aptr[p] = (const char*)xb + (size_t)tok * (DDIM * 2) + cA;
  }
  const char* bgp = wg + wid * 1024 + lane * 16;
  const char* bup = wu + wid * 1024 + lane * 16;
  char* ldsA  = As + wid * 1024;
  char* ldsBg = Bg + wid * 1024;
  char* ldsBu = Bu + wid * 1024;

  v4f ag[4][2] = {};
  v4f au[4][2] = {};

  for (int kt = 0; kt < 12; ++kt) {
#pragma unroll
    for (int p = 0; p < 4; ++p) gload16(aptr[p] + kt * 128, ldsA + p * 4096);
#pragma unroll
    for (int p = 0; p < 2; ++p) gload16(bgp + kt * 16384 + p * 4096, ldsBg + p * 4096);
#pragma unroll
    for (int p = 0; p < 2; ++p) gload16(bup + kt * 16384 + p * 4096, ldsBu + p * 4096);
    __syncthreads();
#pragma unroll
    for (int ks = 0; ks < 2; ++ks) {
      const int colb = ks * 64 + hk * 16;
      v8bf fa[4];
#pragma unroll
      for (int m = 0; m < 4; ++m) {
        const int r = wr * 64 + m * 16 + lr16;
        fa[m] = *(const v8bf*)(As + r * 128 + (colb ^ ((r & 7) << 4)));
      }
#pragma unroll
      for (int n = 0; n < 2; ++n) {
        const int r = wc * 32 + n * 16 + lr16;
        const int sb = r * 128 + (colb ^ ((r & 7) << 4));
        v8bf fg = *(const v8bf*)(Bg + sb);
        v8bf fu = *(const v8bf*)(Bu + sb);
#pragma unroll
        for (int m = 0; m < 4; ++m) {
          ag[m][n] = MFMA_B16(fa[m], fg, ag[m][n]);
          au[m][n] = MFMA_B16(fa[m], fu, au[m][n]);
        }
      }
    }
    __syncthreads();
  }

  // epilogue: h = silu(g*sg) * (u*su), bf16
#pragma unroll
  for (int m = 0; m < 4; ++m) {
#pragma unroll
    for (int j = 0; j < 4; ++j) {
      const int rl = wr * 64 + m * 16 + hk * 4 + j;
      const int rg = tm * 128 + rl;
      if (rg >= count) continue;
      const size_t drow = listE ? (size_t)listE[rg] : (size_t)rg;
      __hip_bfloat16* dst = hout + drow * IDIM + tn * 64 + wc * 32 + lr16;
#pragma unroll
      for (int n = 0; n < 2; ++n) {
        const float g = ag[m][n][j] * sg;
        const float u = au[m][n][j] * su;
        const float h = g / (1.f + __expf(-g)) * u;
        dst[n * 16] = __float2bfloat16(h);
      }
    }
  }
}

// ---------------- unified down GEMM, 128x64 tile, K=2048, atomicAdd into out ----------------
// blocks [0,1536): experts (e=b/192, tm=(b%192)/12, tn=b%12), A = he gathered slots
// blocks [1536,1728): shared expert, A = hs dense
__global__ __launch_bounds__(256, 4)
void down_kernel(const __hip_bfloat16* __restrict__ he, const __hip_bfloat16* __restrict__ hs,
                 const __hip_bfloat16* __restrict__ wdT, const __hip_bfloat16* __restrict__ sdT,
                 const float* __restrict__ es, const float* __restrict__ wt,
                 const int* __restrict__ cnt, const int* __restrict__ lists,
                 float* __restrict__ out)
{
  const int b = blockIdx.x;
  int tm, tn, count;
  const char* wd;
  const __hip_bfloat16* asrc;
  const int* listE = nullptr;
  float sd;
  if (b < 1536) {
    const int e = b / 192; const int r = b % 192; tm = r / 12; tn = r % 12;
    count = cnt[e];
    if (tm * 128 >= count) return;
    wd = (const char*)wdT + (size_t)(e * 6 + (tn >> 1)) * (32 * 16384) + (tn & 1) * 8192;
    listE = lists + e * TDIM;
    sd = es[e * 3 + 2];
    asrc = he;
  } else {
    const int r = b - 1536; tm = r / 12; tn = r % 12;
    count = TDIM;
    wd = (const char*)sdT + (size_t)(tn >> 1) * (32 * 16384) + (tn & 1) * 8192;
    sd = 1.f;
    asrc = hs;
  }

  __shared__ __align__(16) char As[16384];
  __shared__ __align__(16) char Bs[8192];

  const int tid = threadIdx.x;
  const int lane = tid & 63;
  const int wid = tid >> 6;
  const int wr = wid >> 1, wc = wid & 1;
  const int lr16 = lane & 15, hk = lane >> 4;

  const int cA = (((lane & 7) ^ (lane >> 3)) << 4);
  const char* aptr[4];
#pragma unroll
  for (int p = 0; p < 4; ++p) {
    const int row = p * 32 + wid * 8 + (lane >> 3);
    const int rg = tm * 128 + row;
    int srow;
    if (listE) { const int idx = rg < count ? rg : count - 1; srow = listE[idx]; }
    else srow = rg;
    aptr[p] = (const char*)asrc + (size_t)srow * (IDIM * 2) + cA;
  }
  const char* bp = wd + wid * 1024 + lane * 16;
  char* ldsA = As + wid * 1024;
  char* ldsB = Bs + wid * 1024;

  v4f acc[4][2] = {};

  for (int kt = 0; kt < 32; ++kt) {
#pragma unroll
    for (int p = 0; p < 4; ++p) gload16(aptr[p] + kt * 128, ldsA + p * 4096);
#pragma unroll
    for (int p = 0; p < 2; ++p) gload16(bp + kt * 16384 + p * 4096, ldsB + p * 4096);
    __syncthreads();
#pragma unroll
    for (int ks = 0; ks < 2; ++ks) {
      const int colb = ks * 64 + hk * 16;
      v8bf fa[4];
#pragma unroll
      for (int m = 0; m < 4; ++m) {
        const int r = wr * 64 + m * 16 + lr16;
        fa[m] = *(const v8bf*)(As + r * 128 + (colb ^ ((r & 7) << 4)));
      }
#pragma unroll
      for (int n = 0; n < 2; ++n) {
        const int r = wc * 32 + n * 16 + lr16;
        v8bf fb = *(const v8bf*)(Bs + r * 128 + (colb ^ ((r & 7) << 4)));
#pragma unroll
        for (int m = 0; m < 4; ++m) acc[m][n] = MFMA_B16(fa[m], fb, acc[m][n]);
      }
    }
    __syncthreads();
  }

#pragma unroll
  for (int m = 0; m < 4; ++m) {
#pragma unroll
    for (int j = 0; j < 4; ++j) {
      const int rl = wr * 64 + m * 16 + hk * 4 + j;
      const int rg = tm * 128 + rl;
      if (rg >= count) continue;
      int tok; float w;
      if (listE) { const int slot = listE[rg]; tok = slot >> 1; w = wt[slot] * sd; }
      else { tok = rg; w = 1.f; }
      float* dst = out + (size_t)tok * DDIM + tn * 64 + wc * 32 + lr16;
#pragma unroll
      for (int n = 0; n < 2; ++n) atomicAdd(dst + n * 16, acc[m][n][j] * w);
    }
  }
}

extern "C" void kernel_launch(void* const* d_in, const int* in_sizes, int n_in,
                              void* d_out, int out_size, void* d_ws, size_t ws_size,
                              hipStream_t stream)
{
  const float* x   = (const float*)d_in[0];
  const float* rw  = (const float*)d_in[1];
  const float* swg = (const float*)d_in[2];
  const float* swu = (const float*)d_in[3];
  const float* swd = (const float*)d_in[4];
  const int*   qg  = (const int*)d_in[5];
  const int*   qu  = (const int*)d_in[6];
  const int*   qd  = (const int*)d_in[7];
  const float* es  = (const float*)d_in[8];
  float* out = (float*)d_out;

  char* ws = (char*)d_ws;
  size_t off = 0;
  auto alloc = [&](size_t bytes) { void* p = ws + off; off = (off + bytes + 255) & ~(size_t)255; return p; };
  // total ws usage ~= 112 MB
  int*   cnt   = (int*)alloc(NEXP * 4);
  int*   lists = (int*)alloc((size_t)NEXP * TDIM * 4);
  float* wt    = (float*)alloc((size_t)2 * TDIM * 4);
  __hip_bfloat16* xb  = (__hip_bfloat16*)alloc((size_t)TDIM * DDIM * 2);
  __hip_bfloat16* wgT = (__hip_bfloat16*)alloc((size_t)NEXP * 16 * 12 * 8192 * 2);
  __hip_bfloat16* wuT = (__hip_bfloat16*)alloc((size_t)NEXP * 16 * 12 * 8192 * 2);
  __hip_bfloat16* wdT = (__hip_bfloat16*)alloc((size_t)NEXP * 6 * 32 * 8192 * 2);
  __hip_bfloat16* sgT = (__hip_bfloat16*)alloc((size_t)16 * 12 * 8192 * 2);
  __hip_bfloat16* suT = (__hip_bfloat16*)alloc((size_t)16 * 12 * 8192 * 2);
  __hip_bfloat16* sdT = (__hip_bfloat16*)alloc((size_t)6 * 32 * 8192 * 2);
  __hip_bfloat16* hs  = (__hip_bfloat16*)alloc((size_t)TDIM * IDIM * 2);
  __hip_bfloat16* he  = (__hip_bfloat16*)alloc((size_t)2 * TDIM * IDIM * 2);

  hipMemsetAsync(cnt, 0, NEXP * 4, stream);
  hipMemsetAsync(out, 0, (size_t)TDIM * DDIM * 4, stream);

  pack_all_kernel<<<512 + 768 + 5184, 256, 0, stream>>>(qg, qu, qd, swg, swu, swd, x, rw,
                                                        wgT, wuT, wdT, sgT, suT, sdT, xb,
                                                        cnt, lists, wt);

  gateup_kernel<<<4096 + 512, 256, 0, stream>>>(xb, wgT, wuT, sgT, suT, es, cnt, lists, he, hs);
  down_kernel<<<1536 + 192, 256, 0, stream>>>(he, hs, wdT, sdT, es, wt, cnt, lists, out);
}

// Round 7
// 347.562 us; speedup vs baseline: 1.2332x; 1.2332x over previous
//
#include <hip/hip_runtime.h>
#include <hip/hip_bf16.h>

#define TDIM 2048
#define DDIM 768
#define IDIM 2048
#define NEXP 8

typedef __bf16 v8bf __attribute__((ext_vector_type(8)));
typedef float v4f __attribute__((ext_vector_type(4)));
typedef int   v4i __attribute__((ext_vector_type(4)));
typedef float v4ff __attribute__((ext_vector_type(4)));

#define MFMA_B16(A,B,C) __builtin_amdgcn_mfma_f32_16x16x32_bf16(A,B,C,0,0,0)

typedef __attribute__((address_space(1))) const unsigned int* gas_t;
typedef __attribute__((address_space(3))) unsigned int* las_t;

__device__ __forceinline__ void gload16(const void* g, void* l) {
  __builtin_amdgcn_global_load_lds((gas_t)g, (las_t)l, 16, 0, 0);
}

// ================= merged router + x-pack + weight-pack =================
// blocks [0,512):      router, 4 tokens/block (1/wave); wt premultiplied by sd[e]
// blocks [512,1280):   x fp32 -> bf16 (linear)
// blocks [1280,6464):  weight tiles -> bf16 [128 rows][64 cols], XOR-swizzled.
//   gate+up are INTERLEAVED into one N=4096 tensor at 16-row granularity:
//     combined row r: which=(r>>4)&1 (0=gate,1=up), i=(r>>5)*16+(r&15).
//   Tile content: dst byte (row, cb) = source col byte (cb ^ ((row&7)<<4)).
//   Round-4 coalesced mapping + hoisted 8x16B register loads (no nontemporal).
__global__ __launch_bounds__(256)
void pack_all_kernel(const int* __restrict__ qg, const int* __restrict__ qu,
                     const int* __restrict__ qd,
                     const float* __restrict__ sg, const float* __restrict__ su,
                     const float* __restrict__ sd, const float* __restrict__ x,
                     const float* __restrict__ rw, const float* __restrict__ es,
                     __hip_bfloat16* __restrict__ wguT, __hip_bfloat16* __restrict__ sguT,
                     __hip_bfloat16* __restrict__ wdT,  __hip_bfloat16* __restrict__ sdT,
                     __hip_bfloat16* __restrict__ xb,
                     int* __restrict__ cnt, int* __restrict__ lists, float* __restrict__ wt)
{
  const int b = blockIdx.x;
  const int tid = threadIdx.x;

  if (b < 512) {  // ---------------- router ----------------
    const int t = b * 4 + (tid >> 6);
    const int lane = tid & 63;
    const float* xp = x + (size_t)t * DDIM;
    float4 xv0 = *(const float4*)(xp + lane * 4);
    float4 xv1 = *(const float4*)(xp + 256 + lane * 4);
    float4 xv2 = *(const float4*)(xp + 512 + lane * 4);
    float logit[NEXP];
#pragma unroll
    for (int e = 0; e < NEXP; ++e) {
      const float* w = rw + (size_t)e * DDIM;
      float4 w0 = *(const float4*)(w + lane * 4);
      float4 w1 = *(const float4*)(w + 256 + lane * 4);
      float4 w2 = *(const float4*)(w + 512 + lane * 4);
      float p = xv0.x * w0.x + xv0.y * w0.y + xv0.z * w0.z + xv0.w * w0.w
              + xv1.x * w1.x + xv1.y * w1.y + xv1.z * w1.z + xv1.w * w1.w
              + xv2.x * w2.x + xv2.y * w2.y + xv2.z * w2.z + xv2.w * w2.w;
#pragma unroll
      for (int off = 32; off > 0; off >>= 1) p += __shfl_down(p, off, 64);
      logit[e] = p;
    }
    if (lane == 0) {
      float m = logit[0];
#pragma unroll
      for (int e = 1; e < NEXP; ++e) m = fmaxf(m, logit[e]);
      float pr[NEXP];
#pragma unroll
      for (int e = 0; e < NEXP; ++e) pr[e] = expf(logit[e] - m);
      int i0 = 0; float v0 = pr[0];
#pragma unroll
      for (int e = 1; e < NEXP; ++e) if (pr[e] > v0) { v0 = pr[e]; i0 = e; }
      int i1 = -1; float v1 = -1.f;
#pragma unroll
      for (int e = 0; e < NEXP; ++e) if (e != i0 && pr[e] > v1) { v1 = pr[e]; i1 = e; }
      float inv = 1.f / (v0 + v1);
      int p0 = atomicAdd(&cnt[i0], 1);
      lists[i0 * TDIM + p0] = t * 2;       // slot = t*2 + k
      wt[t * 2] = v0 * inv * es[i0 * 3 + 2];        // gate weight * down-scale
      int p1 = atomicAdd(&cnt[i1], 1);
      lists[i1 * TDIM + p1] = t * 2 + 1;
      wt[t * 2 + 1] = v1 * inv * es[i1 * 3 + 2];
    }
    return;
  }

  if (b < 1280) {  // ---------------- x fp32 -> bf16 ----------------
    const size_t i = (size_t)(b - 512) * 2048 + tid * 8;
    float4 a0 = *(const float4*)(x + i);
    float4 a1 = *(const float4*)(x + i + 4);
    v8bf v;
    v[0] = (__bf16)a0.x; v[1] = (__bf16)a0.y; v[2] = (__bf16)a0.z; v[3] = (__bf16)a0.w;
    v[4] = (__bf16)a1.x; v[5] = (__bf16)a1.y; v[6] = (__bf16)a1.z; v[7] = (__bf16)a1.w;
    *(v8bf*)(xb + i) = v;
    return;
  }

  // ---------------- weight tiles ----------------
  const int wb = b - 1280;
  const char *sA, *sB;
  __hip_bfloat16* dst;
  int tnt, kt, isint, paired;
  size_t K;
  if (wb < 3072) {            // expert gate+up interleaved, tiles (e*32+tnt)*12+kt
    const int e = wb / 384, rem = wb % 384; tnt = rem / 12; kt = rem % 12;
    sA = (const char*)(qg + (size_t)e * IDIM * DDIM);
    sB = (const char*)(qu + (size_t)e * IDIM * DDIM);
    dst = wguT + (size_t)wb * 8192; isint = 1; paired = 1; K = DDIM;
  } else if (wb < 3456) {     // shared gate+up
    const int tg = wb - 3072; tnt = tg / 12; kt = tg % 12;
    sA = (const char*)sg; sB = (const char*)su;
    dst = sguT + (size_t)tg * 8192; isint = 0; paired = 1; K = DDIM;
  } else if (wb < 4992) {     // expert down, tiles (e*6+tnt)*32+kt
    const int tg = wb - 3456; const int e = tg / 192, rem = tg % 192; tnt = rem / 32; kt = rem % 32;
    sA = (const char*)(qd + (size_t)e * DDIM * IDIM); sB = sA;
    dst = wdT + (size_t)tg * 8192; isint = 1; paired = 0; K = IDIM;
  } else {                    // shared down
    const int tg = wb - 4992; tnt = tg / 32; kt = tg % 32;
    sA = (const char*)sd; sB = sA;
    dst = sdT + (size_t)tg * 8192; isint = 0; paired = 0; K = IDIM;
  }

  // per-p source addresses (32B contiguous chunk each; wave covers full rows)
  const char* sp[4];
  int qidx[4];
#pragma unroll
  for (int p = 0; p < 4; ++p) {
    const int q = p * 256 + tid;
    const int row = q >> 3;
    const int cb = ((q & 7) * 16) ^ ((row & 7) << 4);
    const int rg = tnt * 128 + row;
    int srcrow, which;
    if (paired) { which = (rg >> 4) & 1; srcrow = (rg >> 5) * 16 + (rg & 15); }
    else        { which = 0; srcrow = rg; }
    const char* base = which ? sB : sA;
    sp[p] = base + ((size_t)srcrow * K + kt * 64 + (cb >> 1)) * 4;
    qidx[p] = q;
  }

  if (isint) {
    v4i r[8];
#pragma unroll
    for (int p = 0; p < 4; ++p) {
      r[2 * p]     = *(const v4i*)sp[p];
      r[2 * p + 1] = *((const v4i*)sp[p] + 1);
    }
#pragma unroll
    for (int p = 0; p < 4; ++p) {
      v8bf v;
      v[0] = (__bf16)(float)r[2 * p][0];     v[1] = (__bf16)(float)r[2 * p][1];
      v[2] = (__bf16)(float)r[2 * p][2];     v[3] = (__bf16)(float)r[2 * p][3];
      v[4] = (__bf16)(float)r[2 * p + 1][0]; v[5] = (__bf16)(float)r[2 * p + 1][1];
      v[6] = (__bf16)(float)r[2 * p + 1][2]; v[7] = (__bf16)(float)r[2 * p + 1][3];
      *(v8bf*)(dst + (size_t)qidx[p] * 8) = v;
    }
  } else {
    v4ff r[8];
#pragma unroll
    for (int p = 0; p < 4; ++p) {
      r[2 * p]     = *(const v4ff*)sp[p];
      r[2 * p + 1] = *((const v4ff*)sp[p] + 1);
    }
#pragma unroll
    for (int p = 0; p < 4; ++p) {
      v8bf v;
      v[0] = (__bf16)r[2 * p][0];     v[1] = (__bf16)r[2 * p][1];
      v[2] = (__bf16)r[2 * p][2];     v[3] = (__bf16)r[2 * p][3];
      v[4] = (__bf16)r[2 * p + 1][0]; v[5] = (__bf16)r[2 * p + 1][1];
      v[6] = (__bf16)r[2 * p + 1][2]; v[7] = (__bf16)r[2 * p + 1][3];
      *(v8bf*)(dst + (size_t)qidx[p] * 8) = v;
    }
  }
}

// ================= gate+up GEMM, 128x128 tile, N=4096 interleaved =================
// blocks [0,4096): experts (e=b>>9, tm=(b>>5)&15, tn=b&31), gathered rows
// blocks [4096,4608): shared expert, dense rows (h rows 4096+t)
// acc[4][4]: fragment pairs (2p,2p+1) hold (gate,up) for the SAME i -> in-register silu.
__global__ __launch_bounds__(256, 3)
void gu_gemm_kernel(const __hip_bfloat16* __restrict__ xb,
                    const __hip_bfloat16* __restrict__ wguT, const __hip_bfloat16* __restrict__ sguT,
                    const float* __restrict__ es,
                    const int* __restrict__ cnt, const int* __restrict__ lists,
                    __hip_bfloat16* __restrict__ h)
{
  const int b = blockIdx.x;
  int tm, tn, count;
  const char* bbase;
  const int* listE = nullptr;
  float sgc, suc;
  if (b < 4096) {
    const int e = b >> 9; tm = (b >> 5) & 15; tn = b & 31;
    count = cnt[e];
    if (tm * 128 >= count) return;
    bbase = (const char*)wguT + (size_t)(e * 32 + tn) * (12 * 16384);
    listE = lists + e * TDIM;
    sgc = es[e * 3 + 0]; suc = es[e * 3 + 1];
  } else {
    const int b2 = b - 4096; tm = b2 >> 5; tn = b2 & 31;
    count = TDIM;
    bbase = (const char*)sguT + (size_t)tn * (12 * 16384);
    sgc = 1.f; suc = 1.f;
  }

  __shared__ __align__(16) char As[16384];
  __shared__ __align__(16) char Bs[16384];

  const int tid = threadIdx.x;
  const int lane = tid & 63;
  const int wid = tid >> 6;
  const int wr = wid >> 1, wc = wid & 1;
  const int lr16 = lane & 15, hk = lane >> 4;

  const int cA = (((lane & 7) ^ (lane >> 3)) << 4);
  const char* aptr[4];
#pragma unroll
  for (int p = 0; p < 4; ++p) {
    const int row = p * 32 + wid * 8 + (lane >> 3);
    const int rg = tm * 128 + row;
    int tok;
    if (listE) { const int idx = rg < count ? rg : count - 1; tok = listE[idx] >> 1; }
    else tok = rg;
    aptr[p] = (const char*)xb + (size_t)tok * (DDIM * 2) + cA;
  }
  const char* bp = bbase + wid * 1024 + lane * 16;

  v4f acc[4][4] = {};

  for (int kt = 0; kt < 12; ++kt) {
#pragma unroll
    for (int p = 0; p < 4; ++p) gload16(aptr[p] + kt * 128, As + wid * 1024 + p * 4096);
#pragma unroll
    for (int p = 0; p < 4; ++p) gload16(bp + kt * 16384 + p * 4096, Bs + wid * 1024 + p * 4096);
    __syncthreads();
#pragma unroll
    for (int ks = 0; ks < 2; ++ks) {
      const int colb = ks * 64 + hk * 16;
      v8bf fa[4], fb[4];
#pragma unroll
      for (int m = 0; m < 4; ++m) {
        const int r = wr * 64 + m * 16 + lr16;
        fa[m] = *(const v8bf*)(As + r * 128 + (colb ^ ((r & 7) << 4)));
      }
#pragma unroll
      for (int n = 0; n < 4; ++n) {
        const int r = wc * 64 + n * 16 + lr16;
        fb[n] = *(const v8bf*)(Bs + r * 128 + (colb ^ ((r & 7) << 4)));
      }
#pragma unroll
      for (int n = 0; n < 4; ++n)
#pragma unroll
        for (int m = 0; m < 4; ++m) acc[m][n] = MFMA_B16(fa[m], fb[n], acc[m][n]);
    }
    __syncthreads();
  }

  // epilogue: pairs (2p,2p+1) = (g,u) for i = (tn*4 + wc*2 + p)*16 + lr16
#pragma unroll
  for (int m = 0; m < 4; ++m) {
#pragma unroll
    for (int j = 0; j < 4; ++j) {
      const int rl = wr * 64 + m * 16 + hk * 4 + j;
      const int rg = tm * 128 + rl;
      if (rg >= count) continue;
      const size_t drow = listE ? (size_t)listE[rg] : (size_t)(4096 + rg);
      __hip_bfloat16* dh = h + drow * IDIM + (tn * 4 + wc * 2) * 16 + lr16;
#pragma unroll
      for (int p = 0; p < 2; ++p) {
        const float g = acc[m][2 * p][j] * sgc;
        const float u = acc[m][2 * p + 1][j] * suc;
        dh[p * 16] = __float2bfloat16(g / (1.f + __expf(-g)) * u);
      }
    }
  }
}

// ================= down GEMM, 128x128 tile, K=2048, atomicAdd into out =================
// blocks [0,768): experts (e=b/96, tm=(b%96)/6, tn=b%6), A = h[slot]
// blocks [768,864): shared expert, A = h[4096+t]
__global__ __launch_bounds__(256, 3)
void down_kernel(const __hip_bfloat16* __restrict__ h,
                 const __hip_bfloat16* __restrict__ wdT, const __hip_bfloat16* __restrict__ sdT,
                 const float* __restrict__ wt,
                 const int* __restrict__ cnt, const int* __restrict__ lists,
                 float* __restrict__ out)
{
  const int b = blockIdx.x;
  int tm, tn, count;
  const char* bbase;
  const int* listE = nullptr;
  if (b < 768) {
    const int e = b / 96; const int r = b % 96; tm = r / 6; tn = r % 6;
    count = cnt[e];
    if (tm * 128 >= count) return;
    bbase = (const char*)wdT + (size_t)(e * 6 + tn) * (32 * 16384);
    listE = lists + e * TDIM;
  } else {
    const int r = b - 768; tm = r / 6; tn = r % 6;
    count = TDIM;
    bbase = (const char*)sdT + (size_t)tn * (32 * 16384);
  }

  __shared__ __align__(16) char As[16384];
  __shared__ __align__(16) char Bs[16384];

  const int tid = threadIdx.x;
  const int lane = tid & 63;
  const int wid = tid >> 6;
  const int wr = wid >> 1, wc = wid & 1;
  const int lr16 = lane & 15, hk = lane >> 4;

  const int cA = (((lane & 7) ^ (lane >> 3)) << 4);
  const char* aptr[4];
#pragma unroll
  for (int p = 0; p < 4; ++p) {
    const int row = p * 32 + wid * 8 + (lane >> 3);
    const int rg = tm * 128 + row;
    int srow;
    if (listE) { const int idx = rg < count ? rg : count - 1; srow = listE[idx]; }
    else srow = 4096 + rg;
    aptr[p] = (const char*)h + (size_t)srow * (IDIM * 2) + cA;
  }
  const char* bp = bbase + wid * 1024 + lane * 16;

  v4f acc[4][4] = {};

  for (int kt = 0; kt < 32; ++kt) {
#pragma unroll
    for (int p = 0; p < 4; ++p) gload16(aptr[p] + kt * 128, As + wid * 1024 + p * 4096);
#pragma unroll
    for (int p = 0; p < 4; ++p) gload16(bp + kt * 16384 + p * 4096, Bs + wid * 1024 + p * 4096);
    __syncthreads();
#pragma unroll
    for (int ks = 0; ks < 2; ++ks) {
      const int colb = ks * 64 + hk * 16;
      v8bf fa[4], fb[4];
#pragma unroll
      for (int m = 0; m < 4; ++m) {
        const int r = wr * 64 + m * 16 + lr16;
        fa[m] = *(const v8bf*)(As + r * 128 + (colb ^ ((r & 7) << 4)));
      }
#pragma unroll
      for (int n = 0; n < 4; ++n) {
        const int r = wc * 64 + n * 16 + lr16;
        fb[n] = *(const v8bf*)(Bs + r * 128 + (colb ^ ((r & 7) << 4)));
      }
#pragma unroll
      for (int n = 0; n < 4; ++n)
#pragma unroll
        for (int m = 0; m < 4; ++m) acc[m][n] = MFMA_B16(fa[m], fb[n], acc[m][n]);
    }
    __syncthreads();
  }

#pragma unroll
  for (int m = 0; m < 4; ++m) {
#pragma unroll
    for (int j = 0; j < 4; ++j) {
      const int rl = wr * 64 + m * 16 + hk * 4 + j;
      const int rg = tm * 128 + rl;
      if (rg >= count) continue;
      int tok; float w;
      if (listE) { const int slot = listE[rg]; tok = slot >> 1; w = wt[slot]; }  // wt pre-multiplied by sd
      else { tok = rg; w = 1.f; }
      float* dst = out + (size_t)tok * DDIM + tn * 128 + wc * 64 + lr16;
#pragma unroll
      for (int n = 0; n < 4; ++n) atomicAdd(dst + n * 16, acc[m][n][j] * w);
    }
  }
}

extern "C" void kernel_launch(void* const* d_in, const int* in_sizes, int n_in,
                              void* d_out, int out_size, void* d_ws, size_t ws_size,
                              hipStream_t stream)
{
  const float* x   = (const float*)d_in[0];
  const float* rw  = (const float*)d_in[1];
  const float* swg = (const float*)d_in[2];
  const float* swu = (const float*)d_in[3];
  const float* swd = (const float*)d_in[4];
  const int*   qg  = (const int*)d_in[5];
  const int*   qu  = (const int*)d_in[6];
  const int*   qd  = (const int*)d_in[7];
  const float* es  = (const float*)d_in[8];
  float* out = (float*)d_out;

  char* ws = (char*)d_ws;
  size_t off = 0;
  auto alloc = [&](size_t bytes) { void* p = ws + off; off = (off + bytes + 255) & ~(size_t)255; return p; };
  // total ws usage ~= 113 MB
  int*   cnt   = (int*)alloc(NEXP * 4);
  int*   lists = (int*)alloc((size_t)NEXP * TDIM * 4);
  float* wt    = (float*)alloc((size_t)2 * TDIM * 4);
  __hip_bfloat16* xb   = (__hip_bfloat16*)alloc((size_t)TDIM * DDIM * 2);
  __hip_bfloat16* wguT = (__hip_bfloat16*)alloc((size_t)NEXP * 32 * 12 * 8192 * 2);
  __hip_bfloat16* sguT = (__hip_bfloat16*)alloc((size_t)32 * 12 * 8192 * 2);
  __hip_bfloat16* wdT  = (__hip_bfloat16*)alloc((size_t)NEXP * 6 * 32 * 8192 * 2);
  __hip_bfloat16* sdT  = (__hip_bfloat16*)alloc((size_t)6 * 32 * 8192 * 2);
  __hip_bfloat16* h    = (__hip_bfloat16*)alloc((size_t)(4096 + TDIM) * IDIM * 2);

  hipMemsetAsync(cnt, 0, NEXP * 4, stream);
  hipMemsetAsync(out, 0, (size_t)TDIM * DDIM * 4, stream);

  pack_all_kernel<<<6464, 256, 0, stream>>>(qg, qu, qd, swg, swu, swd, x, rw, es,
                                            wguT, sguT, wdT, sdT, xb, cnt, lists, wt);
  gu_gemm_kernel<<<4096 + 512, 256, 0, stream>>>(xb, wguT, sguT, es, cnt, lists, h);
  down_kernel<<<768 + 96, 256, 0, stream>>>(h, wdT, sdT, wt, cnt, lists, out);
}